// Round 17
// baseline (181.660 us; speedup 1.0000x reference)
//
#include <hip/hip_runtime.h>

#define T_DIM 8192
#define IN_DIM 4096
#define OUT_DIM 4096
#define R_DIM 64
#define NKP 32   // K-pairs: 128 int4 values each (2 MFMA K-tiles of 64)

typedef int i32x4 __attribute__((ext_vector_type(4)));
typedef float f32x4 __attribute__((ext_vector_type(4)));
typedef _Float16 f16x8 __attribute__((ext_vector_type(8)));

__device__ __forceinline__ int pack4(int4 v) {
  return (v.x & 255) | ((v.y & 255) << 8) | ((v.z & 255) << 16) | ((unsigned)v.w << 24);
}

// global -> LDS direct DMA, 16B per lane (wave-uniform LDS base + lane*16).
__device__ __forceinline__ void gload16(const void* g, void* l) {
  __builtin_amdgcn_global_load_lds(
      (const __attribute__((address_space(1))) void*)(unsigned long long)g,
      (__attribute__((address_space(3))) void*)(unsigned)(unsigned long long)l,
      16, 0, 0);
}

// biased-nibble unpack: 8 packed bytes (2 dwords) -> 16 u8 values in [0,15].
// Same permutation for A and B => cancels in the MFMA dot product.
__device__ __forceinline__ i32x4 unp(int x, int y) {
  i32x4 r;
  r[0] = x & 0x0F0F0F0F;
  r[1] = (x >> 4) & 0x0F0F0F0F;
  r[2] = y & 0x0F0F0F0F;
  r[3] = (y >> 4) & 0x0F0F0F0F;
  return r;
}

__device__ __forceinline__ unsigned pb(int a, int b) {
  return (unsigned)(a + 8) | ((unsigned)(b + 8) << 4);
}

// ---- cvt: int32 int4-values -> swizzled k-pair nibble layout + biased row sums ----
// Row r output (2048B): 32 kpair-blocks of 64B; position p (16B) holds kgroup
// g = p ^ ((r>>1)&3) as [kt_even 8B | kt_odd 8B]. SS[r] = sum(v) + 8*4096.
// (byte-identical to R6-R12 layout, passed refcheck; at HBM roofline ~35us)
__global__ __launch_bounds__(256)
void cvt_pack_kernel(const int* __restrict__ qx, const int* __restrict__ wq,
                     char* __restrict__ pk, int* __restrict__ SS) {
  const int wave = blockIdx.x * 4 + (threadIdx.x >> 6);
  const int l = threadIdx.x & 63;
  const int nw = gridDim.x * 4;
  for (int r = wave; r < T_DIM + OUT_DIM; r += nw) {
    const int* src = (r < T_DIM) ? (qx + (size_t)r * IN_DIM)
                                 : (wq + (size_t)(r - T_DIM) * IN_DIM);
    const int4* src4 = (const int4*)src;
    char* dst = pk + (size_t)r * 2048;
    const int rx = (r >> 1) & 3;
    int s = 0;
#pragma unroll
    for (int i = 0; i < 4; ++i) {
      const int q = i * 64 + l;              // (kt,g) pair index 0..255
      const int kt = q >> 2, g = q & 3;
      int4 s0 = src4[q * 4 + 0], s1 = src4[q * 4 + 1];
      int4 s2 = src4[q * 4 + 2], s3 = src4[q * 4 + 3];
      s += s0.x + s0.y + s0.z + s0.w + s1.x + s1.y + s1.z + s1.w +
           s2.x + s2.y + s2.z + s2.w + s3.x + s3.y + s3.z + s3.w;
      unsigned dw0 = pb(s0.x, s0.y) | (pb(s0.z, s0.w) << 8) |
                     (pb(s1.x, s1.y) << 16) | (pb(s1.z, s1.w) << 24);
      unsigned dw1 = pb(s2.x, s2.y) | (pb(s2.z, s2.w) << 8) |
                     (pb(s3.x, s3.y) << 16) | (pb(s3.z, s3.w) << 24);
      const int off = (kt >> 1) * 64 + ((g ^ rx) << 4) + (kt & 1) * 8;
      *(uint2*)(dst + off) = make_uint2(dw0, dw1);
    }
#pragma unroll
    for (int off = 1; off < 64; off <<= 1) s += __shfl_xor(s, off, 64);
    if (l == 0) SS[r] = s + 8 * IN_DIM;
  }
}

// ---------------- 128x128 nibble-packed i4 GEMM, 8 waves x (32x64) ----------------
// R12's pipeline/LDS/swizzle, re-partitioned: 512 threads = 8 waves (4row x
// 2col), per-wave 32x64, acc[2][4]. Same 48KB (3 kpair bufs), counted vmcnt
// (2 gloads/thread/stage). More waves/SIMD (4-6 vs 2-3) interleave into the
// refill gap (barrier->ds_read->unpack) that capped R12 at ~49% MfmaUtil.
__global__ __launch_bounds__(512, 2)
void w4a4_gemm(const char* __restrict__ A8, const char* __restrict__ B8,
               const int* __restrict__ SS,
               const float* __restrict__ sx, const float* __restrict__ sw,
               const float* __restrict__ ox, const float* __restrict__ ow,
               const float* __restrict__ bias, float* __restrict__ out) {
  __shared__ __align__(16) char smem[49152];

  // 2D-chunked XCD remap (proven: FETCH 260->59MB)
  const int bid = blockIdx.x;
  const int xcd = bid & 7, c = bid >> 3;          // bijective: 2048 % 8 == 0
  const int tn = (xcd & 3) * 8 + (c & 7);
  const int tm = (xcd >> 2) * 32 + (c >> 3);
  const int brow = tm * 128, bcol = tn * 128;

  const int t = threadIdx.x;
  const int w = t >> 6, l = t & 63;
  const int wrow = w >> 1, wcol = w & 1;          // 4 x 2 wave grid, 32x64/wave
  const int l16 = l & 15, lk = l >> 4;

  // staging: A 512 chunks, B 512 chunks; thread t -> row t>>2, chunk t&3 (1 each)
  const char* gA = A8 + (size_t)(brow + (t >> 2)) * 2048 + (t & 3) * 16;
  const char* gB = B8 + (size_t)(bcol + (t >> 2)) * 2048 + (t & 3) * 16;
  char* const dA = smem + t * 16;                 // + buf (A region [0,8192))
  char* const dB = smem + 8192 + t * 16;          // + buf (B region [8192,16384))

  // fragment read bases (64B rows, 16B chunks, XOR involution on (row>>1)&3;
  // wave slabs are multiples of 32 rows and m*16 is 0 mod 8 -> xor const ok)
  const int Ra = wrow * 32 + l16;
  const int Cb = wcol * 64 + l16;
  const char* aR = smem + Ra * 64 + ((lk ^ ((Ra >> 1) & 3)) << 4);          // + buf + m*1024
  const char* bR = smem + 8192 + Cb * 64 + ((lk ^ ((Cb >> 1) & 3)) << 4);   // + buf + n*1024

  i32x4 acc[2][4];
#pragma unroll
  for (int m = 0; m < 2; ++m)
#pragma unroll
    for (int n = 0; n < 4; ++n) acc[m][n] = (i32x4){0, 0, 0, 0};

  auto stage = [&](int kp) {
    const int off = kp << 6;
    const int buf = (kp % 3) * 16384;
    gload16(gA + off, dA + buf);
    gload16(gB + off, dB + buf);
  };

  auto compute = [&](int kp) {
    const int buf = (kp % 3) * 16384;
    const char* sa = aR + buf;
    const char* sb = bR + buf;
    i32x4 ap[2], bp[4];
#pragma unroll
    for (int m = 0; m < 2; ++m) ap[m] = *(const i32x4*)(sa + m * 1024);
#pragma unroll
    for (int n = 0; n < 4; ++n) bp[n] = *(const i32x4*)(sb + n * 1024);
    // kt even
    i32x4 bv[4];
#pragma unroll
    for (int n = 0; n < 4; ++n) bv[n] = unp(bp[n][0], bp[n][1]);
    __builtin_amdgcn_s_setprio(1);
#pragma unroll
    for (int m = 0; m < 2; ++m) {
      i32x4 av = unp(ap[m][0], ap[m][1]);
      acc[m][0] = __builtin_amdgcn_mfma_i32_16x16x64_i8(av, bv[0], acc[m][0], 0, 0, 0);
      acc[m][1] = __builtin_amdgcn_mfma_i32_16x16x64_i8(av, bv[1], acc[m][1], 0, 0, 0);
      acc[m][2] = __builtin_amdgcn_mfma_i32_16x16x64_i8(av, bv[2], acc[m][2], 0, 0, 0);
      acc[m][3] = __builtin_amdgcn_mfma_i32_16x16x64_i8(av, bv[3], acc[m][3], 0, 0, 0);
    }
    __builtin_amdgcn_s_setprio(0);
    // kt odd
#pragma unroll
    for (int n = 0; n < 4; ++n) bv[n] = unp(bp[n][2], bp[n][3]);
    __builtin_amdgcn_s_setprio(1);
#pragma unroll
    for (int m = 0; m < 2; ++m) {
      i32x4 av = unp(ap[m][2], ap[m][3]);
      acc[m][0] = __builtin_amdgcn_mfma_i32_16x16x64_i8(av, bv[0], acc[m][0], 0, 0, 0);
      acc[m][1] = __builtin_amdgcn_mfma_i32_16x16x64_i8(av, bv[1], acc[m][1], 0, 0, 0);
      acc[m][2] = __builtin_amdgcn_mfma_i32_16x16x64_i8(av, bv[2], acc[m][2], 0, 0, 0);
      acc[m][3] = __builtin_amdgcn_mfma_i32_16x16x64_i8(av, bv[3], acc[m][3], 0, 0, 0);
    }
    __builtin_amdgcn_s_setprio(0);
  };

#define VMBAR(N)                                          \
  asm volatile("s_waitcnt vmcnt(" #N ")" ::: "memory");   \
  __builtin_amdgcn_s_barrier();                           \
  __builtin_amdgcn_sched_barrier(0);

  // depth-2 counted pipeline (R12 skeleton, counts halved for 2 gloads/stage):
  // at VMBAR(2) only kp's 2 loads are waited; kp+1's stay in flight across
  // the barrier. stage(kp+2) writes buf[(kp-1)%3], whose last readers
  // (compute(kp-1)) finished their ds_reads before arriving at this barrier.
  stage(0); stage(1);
  for (int kp = 0; kp < NKP - 2; ++kp) {
    VMBAR(2);
    stage(kp + 2);
    compute(kp);
  }
  VMBAR(2);
  compute(NKP - 2);
  VMBAR(0);
  compute(NKP - 1);

  // ---- dequant: acc = accB - 8*SA - 8*SB + 262144, then scales ----
  const int orow0 = brow + wrow * 32 + (lk << 2);
  const int ocol0 = bcol + wcol * 64 + l16;
  const int* SA = SS;
  const int* SB = SS + T_DIM;
  float swv[4], bvv[4];
  int cb[4];
#pragma unroll
  for (int n = 0; n < 4; ++n) {
    swv[n] = sw[ocol0 + n * 16];
    bvv[n] = bias[ocol0 + n * 16];
    cb[n] = -8 * SB[ocol0 + n * 16];
  }

  f32x4 facc[2][4];
#pragma unroll
  for (int m = 0; m < 2; ++m) {
#pragma unroll
    for (int r = 0; r < 4; ++r) {
      const int row = orow0 + m * 16 + r;
      const float sxv = sx[row];
      const int ca = 262144 - 8 * SA[row];
#pragma unroll
      for (int n = 0; n < 4; ++n)
        facc[m][n][r] = (float)(acc[m][n][r] + ca + cb[n]) * sxv * swv[n];
    }
  }

  // ---- outlier rank-64 addmm via f16 MFMA ----
  __syncthreads();   // all waves done with GEMM LDS reads
  // A-f16 [128][64] = 16KB at 0; B-f16 [128][64] = 16KB at 16384; chunk ^= row&7
#pragma unroll
  for (int j = 0; j < 2; ++j) {
    int q = j * 512 + t;
    int row = q >> 3, cd = q & 7, cs = cd ^ (row & 7);
    const float* ga = ox + (size_t)(brow + row) * R_DIM + cs * 8;
    float4 f0 = *(const float4*)ga, f1 = *(const float4*)(ga + 4);
    f16x8 h;
    h[0] = (_Float16)f0.x; h[1] = (_Float16)f0.y; h[2] = (_Float16)f0.z; h[3] = (_Float16)f0.w;
    h[4] = (_Float16)f1.x; h[5] = (_Float16)f1.y; h[6] = (_Float16)f1.z; h[7] = (_Float16)f1.w;
    *(f16x8*)(smem + row * 128 + cd * 16) = h;
    const float* gb = ow + (size_t)(bcol + row) * R_DIM + cs * 8;
    f0 = *(const float4*)gb; f1 = *(const float4*)(gb + 4);
    f16x8 g;
    g[0] = (_Float16)f0.x; g[1] = (_Float16)f0.y; g[2] = (_Float16)f0.z; g[3] = (_Float16)f0.w;
    g[4] = (_Float16)f1.x; g[5] = (_Float16)f1.y; g[6] = (_Float16)f1.z; g[7] = (_Float16)f1.w;
    *(f16x8*)(smem + 16384 + row * 128 + cd * 16) = g;
  }
  __syncthreads();

  const char* qa = smem + (wrow * 32 + l16) * 128;          // + m*2048 (m<2)
  const char* qb = smem + 16384 + (wcol * 64 + l16) * 128;  // + n*2048
  const int x7 = l16 & 7;
#pragma unroll
  for (int s = 0; s < 2; ++s) {
    const int ca2 = ((s * 4 + lk) ^ x7) << 4;
    f16x8 hb[4];
#pragma unroll
    for (int n = 0; n < 4; ++n) hb[n] = *(const f16x8*)(qb + n * 2048 + ca2);
#pragma unroll
    for (int m = 0; m < 2; ++m) {
      f16x8 ha = *(const f16x8*)(qa + m * 2048 + ca2);
#pragma unroll
      for (int n = 0; n < 4; ++n)
        facc[m][n] = __builtin_amdgcn_mfma_f32_16x16x32_f16(ha, hb[n], facc[m][n], 0, 0, 0);
    }
  }

  // ---- store out = facc + bias ----
#pragma unroll
  for (int m = 0; m < 2; ++m)
#pragma unroll
    for (int r = 0; r < 4; ++r) {
      float* po = out + (size_t)(orow0 + m * 16 + r) * OUT_DIM + ocol0;
#pragma unroll
      for (int n = 0; n < 4; ++n) po[n * 16] = facc[m][n][r] + bvv[n];
    }
}

// ---------------- fallback: 128x128, in-register pack (if ws too small) ----------------
__global__ __launch_bounds__(256)
void w4a4_gemm_fb(const int* __restrict__ A32, const int* __restrict__ B32,
                  const float* __restrict__ sx, const float* __restrict__ sw,
                  const float* __restrict__ ox, const float* __restrict__ ow,
                  const float* __restrict__ bias, float* __restrict__ out) {
  __shared__ __align__(16) unsigned char smem[32768];
  char* sA = (char*)smem;
  char* sB = (char*)smem + 8192;

  const int bid = blockIdx.x;
  const int swzb = (bid & 7) * 256 + (bid >> 3);
  const int tm = swzb >> 5, tn = swzb & 31;
  const int brow = tm * 128, bcol = tn * 128;

  const int t = threadIdx.x;
  const int l = t & 63;
  const int wr = (t >> 6) >> 1, wc = (t >> 6) & 1;
  const int l16 = l & 15, lk = l >> 4;

  i32x4 iacc[4][4];
#pragma unroll
  for (int m = 0; m < 4; ++m)
#pragma unroll
    for (int n = 0; n < 4; ++n) iacc[m][n] = (i32x4){0, 0, 0, 0};

  const int ar = t >> 2;
  const int ac = (t & 3) << 4;
  const int* hA0 = A32 + (size_t)(brow + ar) * IN_DIM + ac;
  const int* hA1 = hA0 + (size_t)64 * IN_DIM;
  const int* hB0 = B32 + (size_t)(bcol + ar) * IN_DIM + ac;
  const int* hB1 = hB0 + (size_t)64 * IN_DIM;

  const char* fragA = sA + (size_t)(wr * 64 + l16) * 64 + lk * 16;
  const char* fragB = sB + (size_t)(wc * 64 + l16) * 64 + lk * 16;

  for (int k0 = 0; k0 < IN_DIM; k0 += 64) {
    const int4* pA0 = (const int4*)(hA0 + k0);
    int4 r0 = {pack4(pA0[0]), pack4(pA0[1]), pack4(pA0[2]), pack4(pA0[3])};
    *(int4*)(sA + t * 16) = r0;
    const int4* pA1 = (const int4*)(hA1 + k0);
    int4 r1 = {pack4(pA1[0]), pack4(pA1[1]), pack4(pA1[2]), pack4(pA1[3])};
    *(int4*)(sA + 4096 + t * 16) = r1;
    const int4* pB0 = (const int4*)(hB0 + k0);
    int4 r2 = {pack4(pB0[0]), pack4(pB0[1]), pack4(pB0[2]), pack4(pB0[3])};
    *(int4*)(sB + t * 16) = r2;
    const int4* pB1 = (const int4*)(hB1 + k0);
    int4 r3 = {pack4(pB1[0]), pack4(pB1[1]), pack4(pB1[2]), pack4(pB1[3])};
    *(int4*)(sB + 4096 + t * 16) = r3;
    __syncthreads();
    i32x4 av[4], bv[4];
#pragma unroll
    for (int m = 0; m < 4; ++m) av[m] = *(const i32x4*)(fragA + m * 1024);
#pragma unroll
    for (int n = 0; n < 4; ++n) bv[n] = *(const i32x4*)(fragB + n * 1024);
#pragma unroll
    for (int m = 0; m < 4; ++m)
#pragma unroll
      for (int n = 0; n < 4; ++n)
        iacc[m][n] = __builtin_amdgcn_mfma_i32_16x16x64_i8(av[m], bv[n], iacc[m][n], 0, 0, 0);
    __syncthreads();
  }

  const int orow = brow + wr * 64 + lk * 4;
  const int ocol = bcol + wc * 64 + l16;
  float swv[4], bvv[4];
#pragma unroll
  for (int n = 0; n < 4; ++n) { swv[n] = sw[ocol + n * 16]; bvv[n] = bias[ocol + n * 16]; }

  f32x4 facc[4][4];
#pragma unroll
  for (int m = 0; m < 4; ++m)
#pragma unroll
    for (int r = 0; r < 4; ++r) {
      float sxv = sx[orow + m * 16 + r];
#pragma unroll
      for (int n = 0; n < 4; ++n) facc[m][n][r] = (float)iacc[m][n][r] * sxv * swv[n];
    }

  _Float16* oA = (_Float16*)smem;
  _Float16* oB = (_Float16*)(smem + 16384);
#pragma unroll
  for (int j = 0; j < 4; ++j) {
    int c = j * 256 + t;
    int rr2 = c >> 3, c8 = (c & 7) << 3;
    const float* gp = ox + (size_t)(brow + rr2) * R_DIM + c8;
    float4 f0 = *(const float4*)gp;
    float4 f1 = *(const float4*)(gp + 4);
    f16x8 h;
    h[0] = (_Float16)f0.x; h[1] = (_Float16)f0.y; h[2] = (_Float16)f0.z; h[3] = (_Float16)f0.w;
    h[4] = (_Float16)f1.x; h[5] = (_Float16)f1.y; h[6] = (_Float16)f1.z; h[7] = (_Float16)f1.w;
    *(f16x8*)((char*)oA + (size_t)c * 16) = h;
    const float* gq = ow + (size_t)(bcol + rr2) * R_DIM + c8;
    f0 = *(const float4*)gq; f1 = *(const float4*)(gq + 4);
    f16x8 g;
    g[0] = (_Float16)f0.x; g[1] = (_Float16)f0.y; g[2] = (_Float16)f0.z; g[3] = (_Float16)f0.w;
    g[4] = (_Float16)f1.x; g[5] = (_Float16)f1.y; g[6] = (_Float16)f1.z; g[7] = (_Float16)f1.w;
    *(f16x8*)((char*)oB + (size_t)c * 16) = g;
  }
  __syncthreads();

  const char* qa = (const char*)oA + (size_t)(wr * 64 + l16) * 128 + lk * 16;
  const char* qb = (const char*)oB + (size_t)(wc * 64 + l16) * 128 + lk * 16;
#pragma unroll
  for (int s = 0; s < 2; ++s) {
    f16x8 ha[4], hb[4];
#pragma unroll
    for (int m = 0; m < 4; ++m) ha[m] = *(const f16x8*)(qa + m * 2048 + s * 64);
#pragma unroll
    for (int n = 0; n < 4; ++n) hb[n] = *(const f16x8*)(qb + n * 2048 + s * 64);
#pragma unroll
    for (int m = 0; m < 4; ++m)
#pragma unroll
      for (int n = 0; n < 4; ++n)
        facc[m][n] = __builtin_amdgcn_mfma_f32_16x16x32_f16(ha[m], hb[n], facc[m][n], 0, 0, 0);
  }

#pragma unroll
  for (int m = 0; m < 4; ++m)
#pragma unroll
    for (int r = 0; r < 4; ++r) {
      float* po = out + (size_t)(orow + m * 16 + r) * OUT_DIM + ocol;
#pragma unroll
      for (int n = 0; n < 4; ++n) po[n * 16] = facc[m][n][r] + bvv[n];
    }
}

extern "C" void kernel_launch(void* const* d_in, const int* in_sizes, int n_in,
                              void* d_out, int out_size, void* d_ws, size_t ws_size,
                              hipStream_t stream) {
  const int*   qx   = (const int*)d_in[0];
  const int*   wq   = (const int*)d_in[1];
  const float* sx   = (const float*)d_in[2];
  const float* sw   = (const float*)d_in[3];
  const float* ox   = (const float*)d_in[4];
  const float* ow   = (const float*)d_in[5];
  const float* bias = (const float*)d_in[6];
  float* out = (float*)d_out;

  const size_t packedA = (size_t)T_DIM * 2048;         // 16 MB
  const size_t packedB = (size_t)OUT_DIM * 2048;       // 8 MB
  const size_t ssBytes = (size_t)(T_DIM + OUT_DIM) * 4;
  const size_t need = packedA + packedB + ssBytes;

  if (ws_size >= need) {
    char* pk = (char*)d_ws;                            // A rows then B rows
    int* SS = (int*)(pk + packedA + packedB);
    cvt_pack_kernel<<<768, 256, 0, stream>>>(qx, wq, pk, SS);
    w4a4_gemm<<<2048, 512, 0, stream>>>(pk, pk + packedA, SS, sx, sw, ox, ow, bias, out);
  } else {
    w4a4_gemm_fb<<<2048, 256, 0, stream>>>(qx, wq, sx, sw, ox, ow, bias, out);
  }
}

// Round 18
// 169.525 us; speedup vs baseline: 1.0716x; 1.0716x over previous
//
#include <hip/hip_runtime.h>

#define T_DIM 8192
#define IN_DIM 4096
#define OUT_DIM 4096
#define R_DIM 64
#define NKP 32   // K-pairs: 128 int4 values each (2 MFMA K-tiles of 64)

typedef int i32x4 __attribute__((ext_vector_type(4)));
typedef float f32x4 __attribute__((ext_vector_type(4)));
typedef _Float16 f16x8 __attribute__((ext_vector_type(8)));

__device__ __forceinline__ int pack4(int4 v) {
  return (v.x & 255) | ((v.y & 255) << 8) | ((v.z & 255) << 16) | ((unsigned)v.w << 24);
}

// global -> LDS direct DMA, 16B per lane (wave-uniform LDS base + lane*16).
__device__ __forceinline__ void gload16(const void* g, void* l) {
  __builtin_amdgcn_global_load_lds(
      (const __attribute__((address_space(1))) void*)(unsigned long long)g,
      (__attribute__((address_space(3))) void*)(unsigned)(unsigned long long)l,
      16, 0, 0);
}

// biased-nibble unpack: 8 packed bytes (2 dwords) -> 16 u8 values in [0,15].
// Same permutation for A and B => cancels in the MFMA dot product.
__device__ __forceinline__ i32x4 unp(int x, int y) {
  i32x4 r;
  r[0] = x & 0x0F0F0F0F;
  r[1] = (x >> 4) & 0x0F0F0F0F;
  r[2] = y & 0x0F0F0F0F;
  r[3] = (y >> 4) & 0x0F0F0F0F;
  return r;
}

__device__ __forceinline__ unsigned pb(int a, int b) {
  return (unsigned)(a + 8) | ((unsigned)(b + 8) << 4);
}

// ---- cvt: int32 int4-values -> swizzled k-pair nibble layout + biased row sums ----
// Row r output (2048B): 32 kpair-blocks of 64B; position p (16B) holds kgroup
// g = p ^ ((r>>1)&3) as [kt_even 8B | kt_odd 8B]. SS[r] = sum(v) + 8*4096.
// (byte-identical to R6-R12 layout, passed refcheck; at HBM roofline ~35us)
__global__ __launch_bounds__(256)
void cvt_pack_kernel(const int* __restrict__ qx, const int* __restrict__ wq,
                     char* __restrict__ pk, int* __restrict__ SS) {
  const int wave = blockIdx.x * 4 + (threadIdx.x >> 6);
  const int l = threadIdx.x & 63;
  const int nw = gridDim.x * 4;
  for (int r = wave; r < T_DIM + OUT_DIM; r += nw) {
    const int* src = (r < T_DIM) ? (qx + (size_t)r * IN_DIM)
                                 : (wq + (size_t)(r - T_DIM) * IN_DIM);
    const int4* src4 = (const int4*)src;
    char* dst = pk + (size_t)r * 2048;
    const int rx = (r >> 1) & 3;
    int s = 0;
#pragma unroll
    for (int i = 0; i < 4; ++i) {
      const int q = i * 64 + l;              // (kt,g) pair index 0..255
      const int kt = q >> 2, g = q & 3;
      int4 s0 = src4[q * 4 + 0], s1 = src4[q * 4 + 1];
      int4 s2 = src4[q * 4 + 2], s3 = src4[q * 4 + 3];
      s += s0.x + s0.y + s0.z + s0.w + s1.x + s1.y + s1.z + s1.w +
           s2.x + s2.y + s2.z + s2.w + s3.x + s3.y + s3.z + s3.w;
      unsigned dw0 = pb(s0.x, s0.y) | (pb(s0.z, s0.w) << 8) |
                     (pb(s1.x, s1.y) << 16) | (pb(s1.z, s1.w) << 24);
      unsigned dw1 = pb(s2.x, s2.y) | (pb(s2.z, s2.w) << 8) |
                     (pb(s3.x, s3.y) << 16) | (pb(s3.z, s3.w) << 24);
      const int off = (kt >> 1) * 64 + ((g ^ rx) << 4) + (kt & 1) * 8;
      *(uint2*)(dst + off) = make_uint2(dw0, dw1);
    }
#pragma unroll
    for (int off = 1; off < 64; off <<= 1) s += __shfl_xor(s, off, 64);
    if (l == 0) SS[r] = s + 8 * IN_DIM;
  }
}

// ---------------- 128x128 nibble-packed i4 GEMM (R12 best + ds-read-first) ----------------
// 3 kpair buffers x 16KB = 48KB, counted vmcnt(4), 2D XCD remap, 2 blocks/CU.
// Tweak vs R12: fragment ds_reads for kp are issued BEFORE stage(kp+2)'s
// gloads (same barrier-protected region, identical invariants) so ds latency
// drains under the gload-issue + unpack window.
__global__ __launch_bounds__(256, 2)
void w4a4_gemm(const char* __restrict__ A8, const char* __restrict__ B8,
               const int* __restrict__ SS,
               const float* __restrict__ sx, const float* __restrict__ sw,
               const float* __restrict__ ox, const float* __restrict__ ow,
               const float* __restrict__ bias, float* __restrict__ out) {
  __shared__ __align__(16) char smem[49152];

  // 2D-chunked XCD remap (proven: FETCH 260->59MB)
  const int bid = blockIdx.x;
  const int xcd = bid & 7, c = bid >> 3;          // bijective: 2048 % 8 == 0
  const int tn = (xcd & 3) * 8 + (c & 7);
  const int tm = (xcd >> 2) * 32 + (c >> 3);
  const int brow = tm * 128, bcol = tn * 128;

  const int t = threadIdx.x;
  const int w = t >> 6, l = t & 63;
  const int wr = w >> 1, wc = w & 1;              // 2 x 2 wave grid
  const int l16 = l & 15, lk = l >> 4;

  // staging: A 512 chunks (t, t+256), B 512 chunks (t, t+256); 16B each
  const char* gA0 = A8 + (size_t)(brow + (t >> 2)) * 2048 + (t & 3) * 16;
  const char* gA1 = gA0 + (size_t)64 * 2048;
  const char* gB0 = B8 + (size_t)(bcol + (t >> 2)) * 2048 + (t & 3) * 16;
  const char* gB1 = gB0 + (size_t)64 * 2048;
  char* const dA0 = smem + t * 16;
  char* const dA1 = smem + 4096 + t * 16;
  char* const dB0 = smem + 8192 + t * 16;
  char* const dB1 = smem + 12288 + t * 16;

  // fragment read bases (64B rows, 16B chunks, XOR involution on (row>>1)&3)
  const int Ra = wr * 64 + l16;
  const int Cb = wc * 64 + l16;
  const char* aR = smem + Ra * 64 + ((lk ^ ((Ra >> 1) & 3)) << 4);          // + buf + m*1024
  const char* bR = smem + 8192 + Cb * 64 + ((lk ^ ((Cb >> 1) & 3)) << 4);   // + buf + n*1024

  i32x4 acc[4][4];
#pragma unroll
  for (int m = 0; m < 4; ++m)
#pragma unroll
    for (int n = 0; n < 4; ++n) acc[m][n] = (i32x4){0, 0, 0, 0};

  auto stage = [&](int kp) {
    const int off = kp << 6;
    const int buf = (kp % 3) * 16384;
    gload16(gA0 + off, dA0 + buf);
    gload16(gA1 + off, dA1 + buf);
    gload16(gB0 + off, dB0 + buf);
    gload16(gB1 + off, dB1 + buf);
  };

  i32x4 ap[4], bp[4];

  auto frags = [&](int kp) {                      // 8 ds_read_b128 for kpair kp
    const int buf = (kp % 3) * 16384;
    const char* sa = aR + buf;
    const char* sb = bR + buf;
#pragma unroll
    for (int m = 0; m < 4; ++m) ap[m] = *(const i32x4*)(sa + m * 1024);
#pragma unroll
    for (int n = 0; n < 4; ++n) bp[n] = *(const i32x4*)(sb + n * 1024);
  };

  auto mfmas = [&]() {
    // kt even
    i32x4 bv[4];
#pragma unroll
    for (int n = 0; n < 4; ++n) bv[n] = unp(bp[n][0], bp[n][1]);
    __builtin_amdgcn_s_setprio(1);
#pragma unroll
    for (int m = 0; m < 4; ++m) {
      i32x4 av = unp(ap[m][0], ap[m][1]);
      acc[m][0] = __builtin_amdgcn_mfma_i32_16x16x64_i8(av, bv[0], acc[m][0], 0, 0, 0);
      acc[m][1] = __builtin_amdgcn_mfma_i32_16x16x64_i8(av, bv[1], acc[m][1], 0, 0, 0);
      acc[m][2] = __builtin_amdgcn_mfma_i32_16x16x64_i8(av, bv[2], acc[m][2], 0, 0, 0);
      acc[m][3] = __builtin_amdgcn_mfma_i32_16x16x64_i8(av, bv[3], acc[m][3], 0, 0, 0);
    }
    __builtin_amdgcn_s_setprio(0);
    // kt odd
#pragma unroll
    for (int n = 0; n < 4; ++n) bv[n] = unp(bp[n][2], bp[n][3]);
    __builtin_amdgcn_s_setprio(1);
#pragma unroll
    for (int m = 0; m < 4; ++m) {
      i32x4 av = unp(ap[m][2], ap[m][3]);
      acc[m][0] = __builtin_amdgcn_mfma_i32_16x16x64_i8(av, bv[0], acc[m][0], 0, 0, 0);
      acc[m][1] = __builtin_amdgcn_mfma_i32_16x16x64_i8(av, bv[1], acc[m][1], 0, 0, 0);
      acc[m][2] = __builtin_amdgcn_mfma_i32_16x16x64_i8(av, bv[2], acc[m][2], 0, 0, 0);
      acc[m][3] = __builtin_amdgcn_mfma_i32_16x16x64_i8(av, bv[3], acc[m][3], 0, 0, 0);
    }
    __builtin_amdgcn_s_setprio(0);
  };

#define VMBAR(N)                                          \
  asm volatile("s_waitcnt vmcnt(" #N ")" ::: "memory");   \
  __builtin_amdgcn_s_barrier();                           \
  __builtin_amdgcn_sched_barrier(0);

  // depth-2 counted pipeline (R12 skeleton, proven correct):
  // at VMBAR(4) only kp's 4 loads are waited; kp+1's stay in flight across
  // the barrier. stage(kp+2) writes buf[(kp-1)%3], whose last readers
  // (compute(kp-1)) finished their ds_reads before arriving at this barrier.
  stage(0); stage(1);
  for (int kp = 0; kp < NKP - 2; ++kp) {
    VMBAR(4);
    frags(kp);        // ds_reads first: latency drains under stage-issue+unpack
    stage(kp + 2);
    mfmas();
  }
  VMBAR(4);
  frags(NKP - 2);
  mfmas();
  VMBAR(0);
  frags(NKP - 1);
  mfmas();

  // ---- dequant: acc = accB - 8*SA - 8*SB + 262144, then scales ----
  const int orow0 = brow + wr * 64 + (lk << 2);
  const int ocol0 = bcol + wc * 64 + l16;
  const int* SA = SS;
  const int* SB = SS + T_DIM;
  float swv[4], bvv[4];
  int cb[4];
#pragma unroll
  for (int n = 0; n < 4; ++n) {
    swv[n] = sw[ocol0 + n * 16];
    bvv[n] = bias[ocol0 + n * 16];
    cb[n] = -8 * SB[ocol0 + n * 16];
  }

  f32x4 facc[4][4];
#pragma unroll
  for (int m = 0; m < 4; ++m) {
#pragma unroll
    for (int r = 0; r < 4; ++r) {
      const int row = orow0 + m * 16 + r;
      const float sxv = sx[row];
      const int ca = 262144 - 8 * SA[row];
#pragma unroll
      for (int n = 0; n < 4; ++n)
        facc[m][n][r] = (float)(acc[m][n][r] + ca + cb[n]) * sxv * swv[n];
    }
  }

  // ---- outlier rank-64 addmm via f16 MFMA ----
  __syncthreads();   // all waves done with GEMM LDS reads
  // A-f16 [128][64] = 16KB at 0; B-f16 [128][64] = 16KB at 16384; chunk ^= row&7
#pragma unroll
  for (int j = 0; j < 4; ++j) {
    int q = j * 256 + t;
    int row = q >> 3, cd = q & 7, cs = cd ^ (row & 7);
    const float* ga = ox + (size_t)(brow + row) * R_DIM + cs * 8;
    float4 f0 = *(const float4*)ga, f1 = *(const float4*)(ga + 4);
    f16x8 h;
    h[0] = (_Float16)f0.x; h[1] = (_Float16)f0.y; h[2] = (_Float16)f0.z; h[3] = (_Float16)f0.w;
    h[4] = (_Float16)f1.x; h[5] = (_Float16)f1.y; h[6] = (_Float16)f1.z; h[7] = (_Float16)f1.w;
    *(f16x8*)(smem + row * 128 + cd * 16) = h;
    const float* gb = ow + (size_t)(bcol + row) * R_DIM + cs * 8;
    f0 = *(const float4*)gb; f1 = *(const float4*)(gb + 4);
    f16x8 g;
    g[0] = (_Float16)f0.x; g[1] = (_Float16)f0.y; g[2] = (_Float16)f0.z; g[3] = (_Float16)f0.w;
    g[4] = (_Float16)f1.x; g[5] = (_Float16)f1.y; g[6] = (_Float16)f1.z; g[7] = (_Float16)f1.w;
    *(f16x8*)(smem + 16384 + row * 128 + cd * 16) = g;
  }
  __syncthreads();

  const char* qa = smem + (wr * 64 + l16) * 128;            // + m*2048
  const char* qb = smem + 16384 + (wc * 64 + l16) * 128;    // + n*2048
  const int x7 = l16 & 7;
#pragma unroll
  for (int s = 0; s < 2; ++s) {
    const int ca2 = ((s * 4 + lk) ^ x7) << 4;
    f16x8 hb[4];
#pragma unroll
    for (int n = 0; n < 4; ++n) hb[n] = *(const f16x8*)(qb + n * 2048 + ca2);
#pragma unroll
    for (int m = 0; m < 4; ++m) {
      f16x8 ha = *(const f16x8*)(qa + m * 2048 + ca2);
#pragma unroll
      for (int n = 0; n < 4; ++n)
        facc[m][n] = __builtin_amdgcn_mfma_f32_16x16x32_f16(ha, hb[n], facc[m][n], 0, 0, 0);
    }
  }

  // ---- store out = facc + bias ----
#pragma unroll
  for (int m = 0; m < 4; ++m)
#pragma unroll
    for (int r = 0; r < 4; ++r) {
      float* po = out + (size_t)(orow0 + m * 16 + r) * OUT_DIM + ocol0;
#pragma unroll
      for (int n = 0; n < 4; ++n) po[n * 16] = facc[m][n][r] + bvv[n];
    }
}

// ---------------- fallback: 128x128, in-register pack (if ws too small) ----------------
__global__ __launch_bounds__(256)
void w4a4_gemm_fb(const int* __restrict__ A32, const int* __restrict__ B32,
                  const float* __restrict__ sx, const float* __restrict__ sw,
                  const float* __restrict__ ox, const float* __restrict__ ow,
                  const float* __restrict__ bias, float* __restrict__ out) {
  __shared__ __align__(16) unsigned char smem[32768];
  char* sA = (char*)smem;
  char* sB = (char*)smem + 8192;

  const int bid = blockIdx.x;
  const int swzb = (bid & 7) * 256 + (bid >> 3);
  const int tm = swzb >> 5, tn = swzb & 31;
  const int brow = tm * 128, bcol = tn * 128;

  const int t = threadIdx.x;
  const int l = t & 63;
  const int wr = (t >> 6) >> 1, wc = (t >> 6) & 1;
  const int l16 = l & 15, lk = l >> 4;

  i32x4 iacc[4][4];
#pragma unroll
  for (int m = 0; m < 4; ++m)
#pragma unroll
    for (int n = 0; n < 4; ++n) iacc[m][n] = (i32x4){0, 0, 0, 0};

  const int ar = t >> 2;
  const int ac = (t & 3) << 4;
  const int* hA0 = A32 + (size_t)(brow + ar) * IN_DIM + ac;
  const int* hA1 = hA0 + (size_t)64 * IN_DIM;
  const int* hB0 = B32 + (size_t)(bcol + ar) * IN_DIM + ac;
  const int* hB1 = hB0 + (size_t)64 * IN_DIM;

  const char* fragA = sA + (size_t)(wr * 64 + l16) * 64 + lk * 16;
  const char* fragB = sB + (size_t)(wc * 64 + l16) * 64 + lk * 16;

  for (int k0 = 0; k0 < IN_DIM; k0 += 64) {
    const int4* pA0 = (const int4*)(hA0 + k0);
    int4 r0 = {pack4(pA0[0]), pack4(pA0[1]), pack4(pA0[2]), pack4(pA0[3])};
    *(int4*)(sA + t * 16) = r0;
    const int4* pA1 = (const int4*)(hA1 + k0);
    int4 r1 = {pack4(pA1[0]), pack4(pA1[1]), pack4(pA1[2]), pack4(pA1[3])};
    *(int4*)(sA + 4096 + t * 16) = r1;
    const int4* pB0 = (const int4*)(hB0 + k0);
    int4 r2 = {pack4(pB0[0]), pack4(pB0[1]), pack4(pB0[2]), pack4(pB0[3])};
    *(int4*)(sB + t * 16) = r2;
    const int4* pB1 = (const int4*)(hB1 + k0);
    int4 r3 = {pack4(pB1[0]), pack4(pB1[1]), pack4(pB1[2]), pack4(pB1[3])};
    *(int4*)(sB + 4096 + t * 16) = r3;
    __syncthreads();
    i32x4 av[4], bv[4];
#pragma unroll
    for (int m = 0; m < 4; ++m) av[m] = *(const i32x4*)(fragA + m * 1024);
#pragma unroll
    for (int n = 0; n < 4; ++n) bv[n] = *(const i32x4*)(fragB + n * 1024);
#pragma unroll
    for (int m = 0; m < 4; ++m)
#pragma unroll
      for (int n = 0; n < 4; ++n)
        iacc[m][n] = __builtin_amdgcn_mfma_i32_16x16x64_i8(av[m], bv[n], iacc[m][n], 0, 0, 0);
    __syncthreads();
  }

  const int orow = brow + wr * 64 + lk * 4;
  const int ocol = bcol + wc * 64 + l16;
  float swv[4], bvv[4];
#pragma unroll
  for (int n = 0; n < 4; ++n) { swv[n] = sw[ocol + n * 16]; bvv[n] = bias[ocol + n * 16]; }

  f32x4 facc[4][4];
#pragma unroll
  for (int m = 0; m < 4; ++m)
#pragma unroll
    for (int r = 0; r < 4; ++r) {
      float sxv = sx[orow + m * 16 + r];
#pragma unroll
      for (int n = 0; n < 4; ++n) facc[m][n][r] = (float)iacc[m][n][r] * sxv * swv[n];
    }

  _Float16* oA = (_Float16*)smem;
  _Float16* oB = (_Float16*)(smem + 16384);
#pragma unroll
  for (int j = 0; j < 4; ++j) {
    int c = j * 256 + t;
    int rr2 = c >> 3, c8 = (c & 7) << 3;
    const float* gp = ox + (size_t)(brow + rr2) * R_DIM + c8;
    float4 f0 = *(const float4*)gp;
    float4 f1 = *(const float4*)(gp + 4);
    f16x8 h;
    h[0] = (_Float16)f0.x; h[1] = (_Float16)f0.y; h[2] = (_Float16)f0.z; h[3] = (_Float16)f0.w;
    h[4] = (_Float16)f1.x; h[5] = (_Float16)f1.y; h[6] = (_Float16)f1.z; h[7] = (_Float16)f1.w;
    *(f16x8*)((char*)oA + (size_t)c * 16) = h;
    const float* gq = ow + (size_t)(bcol + rr2) * R_DIM + c8;
    f0 = *(const float4*)gq; f1 = *(const float4*)(gq + 4);
    f16x8 g;
    g[0] = (_Float16)f0.x; g[1] = (_Float16)f0.y; g[2] = (_Float16)f0.z; g[3] = (_Float16)f0.w;
    g[4] = (_Float16)f1.x; g[5] = (_Float16)f1.y; g[6] = (_Float16)f1.z; g[7] = (_Float16)f1.w;
    *(f16x8*)((char*)oB + (size_t)c * 16) = g;
  }
  __syncthreads();

  const char* qa = (const char*)oA + (size_t)(wr * 64 + l16) * 128 + lk * 16;
  const char* qb = (const char*)oB + (size_t)(wc * 64 + l16) * 128 + lk * 16;
#pragma unroll
  for (int s = 0; s < 2; ++s) {
    f16x8 ha[4], hb[4];
#pragma unroll
    for (int m = 0; m < 4; ++m) ha[m] = *(const f16x8*)(qa + m * 2048 + s * 64);
#pragma unroll
    for (int n = 0; n < 4; ++n) hb[n] = *(const f16x8*)(qb + n * 2048 + s * 64);
#pragma unroll
    for (int m = 0; m < 4; ++m)
#pragma unroll
      for (int n = 0; n < 4; ++n)
        facc[m][n] = __builtin_amdgcn_mfma_f32_16x16x32_f16(ha[m], hb[n], facc[m][n], 0, 0, 0);
  }

#pragma unroll
  for (int m = 0; m < 4; ++m)
#pragma unroll
    for (int r = 0; r < 4; ++r) {
      float* po = out + (size_t)(orow + m * 16 + r) * OUT_DIM + ocol;
#pragma unroll
      for (int n = 0; n < 4; ++n) po[n * 16] = facc[m][n][r] + bvv[n];
    }
}

extern "C" void kernel_launch(void* const* d_in, const int* in_sizes, int n_in,
                              void* d_out, int out_size, void* d_ws, size_t ws_size,
                              hipStream_t stream) {
  const int*   qx   = (const int*)d_in[0];
  const int*   wq   = (const int*)d_in[1];
  const float* sx   = (const float*)d_in[2];
  const float* sw   = (const float*)d_in[3];
  const float* ox   = (const float*)d_in[4];
  const float* ow   = (const float*)d_in[5];
  const float* bias = (const float*)d_in[6];
  float* out = (float*)d_out;

  const size_t packedA = (size_t)T_DIM * 2048;         // 16 MB
  const size_t packedB = (size_t)OUT_DIM * 2048;       // 8 MB
  const size_t ssBytes = (size_t)(T_DIM + OUT_DIM) * 4;
  const size_t need = packedA + packedB + ssBytes;

  if (ws_size >= need) {
    char* pk = (char*)d_ws;                            // A rows then B rows
    int* SS = (int*)(pk + packedA + packedB);
    cvt_pack_kernel<<<768, 256, 0, stream>>>(qx, wq, pk, SS);
    w4a4_gemm<<<2048, 256, 0, stream>>>(pk, pk + packedA, SS, sx, sw, ox, ow, bias, out);
  } else {
    w4a4_gemm_fb<<<2048, 256, 0, stream>>>(qx, wq, sx, sw, ox, ow, bias, out);
  }
}